// Round 1
// baseline (2186.662 us; speedup 1.0000x reference)
//
#include <hip/hip_runtime.h>
#include <hip/hip_bf16.h>

typedef __attribute__((ext_vector_type(8))) short bf16x8;
typedef __attribute__((ext_vector_type(4))) float f32x4;
typedef __hip_bfloat16 bf16;

#define S_LEN 2048
#define HIDDEN 4096
#define NH 32
#define NKV 8
#define DH 128
#define ROTD 64
#define ATT_SCALE 0.08838834764831845f   // 128^-0.5
#define RMS_EPS 1e-6f

static __device__ __forceinline__ unsigned short f2bu(float f) {
    bf16 h = __float2bfloat16(f);
    return __builtin_bit_cast(unsigned short, h);
}

// ---------------- fp32 -> bf16 cast (vectorized float4) ----------------
__global__ __launch_bounds__(256) void cast_f32_bf16(const float* __restrict__ src,
                                                     unsigned short* __restrict__ dst, int n4) {
    int i = blockIdx.x * 256 + threadIdx.x;
    if (i >= n4) return;
    float4 v = reinterpret_cast<const float4*>(src)[i];
    ushort4 o;
    o.x = f2bu(v.x); o.y = f2bu(v.y); o.z = f2bu(v.z); o.w = f2bu(v.w);
    reinterpret_cast<ushort4*>(dst)[i] = o;
}

// ---------------- C[M,N] = A[M,K] @ B[N,K]^T  (bf16 in, OutT out) ----------------
// wave computes 16 rows x 64 cols. block = 4 waves (64 rows). grid = (N/64, M/64).
template <typename OutT>
__global__ __launch_bounds__(256) void gemm_bt(const bf16* __restrict__ A,
                                               const bf16* __restrict__ B,
                                               OutT* __restrict__ C,
                                               int M, int N, int K) {
    const int lane = threadIdx.x & 63;
    const int wave = threadIdx.x >> 6;
    const int lq   = lane & 15;
    const int quad = lane >> 4;
    const int m0 = blockIdx.y * 64 + wave * 16;
    const int n0 = blockIdx.x * 64;

    f32x4 acc[4];
#pragma unroll
    for (int t = 0; t < 4; ++t) acc[t] = (f32x4){0.f, 0.f, 0.f, 0.f};

    const bf16* arow = A + (size_t)(m0 + lq) * K + quad * 8;
    const bf16* brow = B + (size_t)(n0 + lq) * K + quad * 8;

    for (int k0 = 0; k0 < K; k0 += 32) {
        bf16x8 af = *reinterpret_cast<const bf16x8*>(arow + k0);
#pragma unroll
        for (int t = 0; t < 4; ++t) {
            bf16x8 bfv = *reinterpret_cast<const bf16x8*>(brow + (size_t)t * 16 * K + k0);
            acc[t] = __builtin_amdgcn_mfma_f32_16x16x32_bf16(af, bfv, acc[t], 0, 0, 0);
        }
    }

#pragma unroll
    for (int t = 0; t < 4; ++t)
#pragma unroll
        for (int r = 0; r < 4; ++r) {
            float v = acc[t][r];
            size_t idx = (size_t)(m0 + quad * 4 + r) * N + n0 + 16 * t + lq;
            if constexpr (sizeof(OutT) == 2) C[idx] = __float2bfloat16(v);
            else                             C[idx] = v;
        }
}

// ---------------- fused RMSNorm + partial RoPE (in place) ----------------
// one wave per (s, head) row of 128; lane holds d=lane and d=lane+64.
__global__ __launch_bounds__(256) void norm_rope(bf16* __restrict__ buf,
                                                 const float* __restrict__ w,
                                                 const float* __restrict__ cosp,
                                                 const float* __restrict__ sinp,
                                                 int log2nh) {
    const int lane = threadIdx.x & 63;
    const int wave = threadIdx.x >> 6;
    const int row  = blockIdx.x * 4 + wave;
    const int s    = row >> log2nh;

    float x1 = __bfloat162float(buf[(size_t)row * DH + lane]);
    float x2 = __bfloat162float(buf[(size_t)row * DH + 64 + lane]);

    float ss = x1 * x1 + x2 * x2;
#pragma unroll
    for (int off = 1; off < 64; off <<= 1) ss += __shfl_xor(ss, off);
    float rs = rsqrtf(ss * (1.0f / 128.0f) + RMS_EPS);

    float y1 = x1 * rs * w[lane];
    float y2 = x2 * rs * w[64 + lane];

    // RoPE on dims [0,64): rotate_half over the 64-dim rot section
    float partner = __shfl_xor(y1, 32);
    float c  = cosp[(size_t)s * ROTD + lane];
    float sn = sinp[(size_t)s * ROTD + lane];
    float rot = (lane < 32) ? (y1 * c - partner * sn) : (y1 * c + partner * sn);

    buf[(size_t)row * DH + lane]      = __float2bfloat16(rot);
    buf[(size_t)row * DH + 64 + lane] = __float2bfloat16(y2);
}

// ---------------- V transpose: v(S, NKV*DH) -> vt(NKV*DH, S) ----------------
__global__ __launch_bounds__(256) void transpose_v(const bf16* __restrict__ v,
                                                   bf16* __restrict__ vt) {
    __shared__ bf16 t[32][65];
    const int c0 = blockIdx.x * 32;   // column tile in (kv*128+d)
    const int s0 = blockIdx.y * 64;   // s tile
    {
        const int j  = threadIdx.x & 31;   // c
        const int i0 = threadIdx.x >> 5;   // 0..7
#pragma unroll
        for (int p = 0; p < 8; ++p) {
            int si = p * 8 + i0;
            t[j][si] = v[(size_t)(s0 + si) * (NKV * DH) + c0 + j];
        }
    }
    __syncthreads();
    {
        const int ii = threadIdx.x & 63;
        const int j0 = threadIdx.x >> 6;   // 0..3
#pragma unroll
        for (int p = 0; p < 8; ++p) {
            int c = p * 4 + j0;
            vt[(size_t)(c0 + c) * S_LEN + s0 + ii] = t[c][ii];
        }
    }
}

// ---------------- MFMA flash attention (causal, GQA) ----------------
// one wave per (head, 16 q rows). k-tiles of 32. per-wave LDS for P C->A transpose.
__global__ __launch_bounds__(256) void flash_attn(const bf16* __restrict__ Q,
                                                  const bf16* __restrict__ Kc,
                                                  const bf16* __restrict__ VT,
                                                  bf16* __restrict__ O) {
    __shared__ bf16 pbuf[4][16 * 32];
    const int lane = threadIdx.x & 63;
    const int wave = threadIdx.x >> 6;
    const int lq   = lane & 15;
    const int quad = lane >> 4;

    const int w  = blockIdx.x * 4 + wave;
    const int h  = w >> 7;                 // 0..31
    const int qt = 127 - (w & 127);        // heavy tiles first
    const int q0 = qt * 16;
    const int kvh = h >> 2;                // GQA: rep = 4

    // Q fragments (16 rows x 128 d), A-layout
    bf16x8 qf[4];
    const bf16* qrow = Q + ((size_t)(q0 + lq) * NH + h) * DH + quad * 8;
#pragma unroll
    for (int i = 0; i < 4; ++i) qf[i] = *reinterpret_cast<const bf16x8*>(qrow + 32 * i);

    f32x4 o[8];
#pragma unroll
    for (int t2 = 0; t2 < 8; ++t2) o[t2] = (f32x4){0.f, 0.f, 0.f, 0.f};
    float m_i[4], l_i[4];
#pragma unroll
    for (int r = 0; r < 4; ++r) { m_i[r] = -1e30f; l_i[r] = 0.f; }

    bf16* pb = pbuf[wave];

    for (int k0 = 0; k0 < q0 + 16; k0 += 32) {
        float p[2][4];
#pragma unroll
        for (int t = 0; t < 2; ++t) {
            f32x4 sacc = (f32x4){0.f, 0.f, 0.f, 0.f};
            const int kc = k0 + 16 * t;
            int krow = kc + lq; if (krow > S_LEN - 1) krow = S_LEN - 1;  // masked anyway
            const bf16* kp = Kc + ((size_t)krow * NKV + kvh) * DH + quad * 8;
#pragma unroll
            for (int i = 0; i < 4; ++i) {
                bf16x8 kf = *reinterpret_cast<const bf16x8*>(kp + 32 * i);
                sacc = __builtin_amdgcn_mfma_f32_16x16x32_bf16(qf[i], kf, sacc, 0, 0, 0);
            }
#pragma unroll
            for (int r = 0; r < 4; ++r) {
                int qi = q0 + quad * 4 + r;
                int ki = kc + lq;
                float sv = sacc[r] * ATT_SCALE;
                p[t][r] = (ki > qi) ? -1e30f : sv;
            }
        }
        // row max over 32 cols (intra-quad butterfly)
        float rowmax[4];
#pragma unroll
        for (int r = 0; r < 4; ++r) rowmax[r] = fmaxf(p[0][r], p[1][r]);
#pragma unroll
        for (int off = 1; off < 16; off <<= 1)
#pragma unroll
            for (int r = 0; r < 4; ++r) rowmax[r] = fmaxf(rowmax[r], __shfl_xor(rowmax[r], off));

        float alpha[4];
#pragma unroll
        for (int r = 0; r < 4; ++r) {
            float mn = fmaxf(m_i[r], rowmax[r]);
            alpha[r] = __expf(m_i[r] - mn);
            m_i[r] = mn;
        }
#pragma unroll
        for (int t = 0; t < 2; ++t)
#pragma unroll
            for (int r = 0; r < 4; ++r) p[t][r] = __expf(p[t][r] - m_i[r]);

        float rsum[4];
#pragma unroll
        for (int r = 0; r < 4; ++r) rsum[r] = p[0][r] + p[1][r];
#pragma unroll
        for (int off = 1; off < 16; off <<= 1)
#pragma unroll
            for (int r = 0; r < 4; ++r) rsum[r] += __shfl_xor(rsum[r], off);
#pragma unroll
        for (int r = 0; r < 4; ++r) l_i[r] = l_i[r] * alpha[r] + rsum[r];

        // P (C-layout) -> LDS row-major 16x32 -> A-layout fragment
#pragma unroll
        for (int t = 0; t < 2; ++t)
#pragma unroll
            for (int r = 0; r < 4; ++r)
                pb[(quad * 4 + r) * 32 + t * 16 + lq] = __float2bfloat16(p[t][r]);
        __threadfence_block();
        bf16x8 pa = *reinterpret_cast<const bf16x8*>(pb + lq * 32 + quad * 8);

        // O = O*alpha + P @ V  (V via VT, k-contiguous)
        const bf16* vp = VT + ((size_t)(kvh * DH + lq)) * S_LEN + k0 + quad * 8;
#pragma unroll
        for (int t2 = 0; t2 < 8; ++t2) {
            f32x4 ot = o[t2];
#pragma unroll
            for (int r = 0; r < 4; ++r) ot[r] *= alpha[r];
            bf16x8 vf = *reinterpret_cast<const bf16x8*>(vp + (size_t)t2 * 16 * S_LEN);
            o[t2] = __builtin_amdgcn_mfma_f32_16x16x32_bf16(pa, vf, ot, 0, 0, 0);
        }
        __threadfence_block();   // keep next iter's P writes after this iter's reads
    }

#pragma unroll
    for (int r = 0; r < 4; ++r) l_i[r] = 1.0f / l_i[r];
#pragma unroll
    for (int t2 = 0; t2 < 8; ++t2)
#pragma unroll
        for (int r = 0; r < 4; ++r)
            O[(size_t)(q0 + quad * 4 + r) * (NH * DH) + h * DH + t2 * 16 + lq] =
                __float2bfloat16(o[t2][r] * l_i[r]);
}

extern "C" void kernel_launch(void* const* d_in, const int* in_sizes, int n_in,
                              void* d_out, int out_size, void* d_ws, size_t ws_size,
                              hipStream_t stream) {
    const float* hs   = (const float*)d_in[0];
    const float* cosp = (const float*)d_in[1];
    const float* sinp = (const float*)d_in[2];
    const float* Wq   = (const float*)d_in[3];
    const float* Wk   = (const float*)d_in[4];
    const float* Wv   = (const float*)d_in[5];
    const float* Wo   = (const float*)d_in[6];
    const float* qw   = (const float*)d_in[7];
    const float* kw   = (const float*)d_in[8];
    float* out = (float*)d_out;

    char* ws = (char*)d_ws;
    size_t off = 0;
    auto carve = [&](size_t bytes) { char* p = ws + off; off += (bytes + 255) & ~(size_t)255; return p; };

    bf16* hsb = (bf16*)carve((size_t)S_LEN * HIDDEN * 2);          // hidden bf16; later reused as AO
    bf16* wqb = (bf16*)carve((size_t)NH * DH * HIDDEN * 2);
    bf16* wkb = (bf16*)carve((size_t)NKV * DH * HIDDEN * 2);
    bf16* wvb = (bf16*)carve((size_t)NKV * DH * HIDDEN * 2);
    bf16* qb  = (bf16*)carve((size_t)S_LEN * NH * DH * 2);         // Q, normed in place
    bf16* kb  = (bf16*)carve((size_t)S_LEN * NKV * DH * 2);        // K, normed in place
    bf16* vb  = (bf16*)carve((size_t)S_LEN * NKV * DH * 2);
    bf16* vtb = (bf16*)carve((size_t)NKV * DH * S_LEN * 2);
    bf16* wob = (bf16*)carve((size_t)HIDDEN * NH * DH * 2);        // after vtb: absorbs tail overreads

    // 1. casts
    cast_f32_bf16<<<(S_LEN * HIDDEN / 4 + 255) / 256, 256, 0, stream>>>(hs, (unsigned short*)hsb, S_LEN * HIDDEN / 4);
    cast_f32_bf16<<<(NH * DH * HIDDEN / 4 + 255) / 256, 256, 0, stream>>>(Wq, (unsigned short*)wqb, NH * DH * HIDDEN / 4);
    cast_f32_bf16<<<(NKV * DH * HIDDEN / 4 + 255) / 256, 256, 0, stream>>>(Wk, (unsigned short*)wkb, NKV * DH * HIDDEN / 4);
    cast_f32_bf16<<<(NKV * DH * HIDDEN / 4 + 255) / 256, 256, 0, stream>>>(Wv, (unsigned short*)wvb, NKV * DH * HIDDEN / 4);
    cast_f32_bf16<<<(HIDDEN * NH * DH / 4 + 255) / 256, 256, 0, stream>>>(Wo, (unsigned short*)wob, HIDDEN * NH * DH / 4);

    // 2. projections (bf16 out)
    gemm_bt<bf16><<<dim3(NH * DH / 64, S_LEN / 64), 256, 0, stream>>>(hsb, wqb, qb, S_LEN, NH * DH, HIDDEN);
    gemm_bt<bf16><<<dim3(NKV * DH / 64, S_LEN / 64), 256, 0, stream>>>(hsb, wkb, kb, S_LEN, NKV * DH, HIDDEN);
    gemm_bt<bf16><<<dim3(NKV * DH / 64, S_LEN / 64), 256, 0, stream>>>(hsb, wvb, vb, S_LEN, NKV * DH, HIDDEN);

    // 3. rmsnorm + rope (in place)
    norm_rope<<<S_LEN * NH / 4, 256, 0, stream>>>(qb, qw, cosp, sinp, 5);
    norm_rope<<<S_LEN * NKV / 4, 256, 0, stream>>>(kb, kw, cosp, sinp, 3);

    // 4. V transpose
    transpose_v<<<dim3(NKV * DH / 32, S_LEN / 64), 256, 0, stream>>>(vb, vtb);

    // 5. flash attention -> AO (reuse hsb)
    bf16* aob = hsb;
    flash_attn<<<NH * (S_LEN / 16) / 4, 256, 0, stream>>>(qb, kb, vtb, aob);

    // 6. output projection (fp32 out)
    gemm_bt<float><<<dim3(HIDDEN / 64, S_LEN / 64), 256, 0, stream>>>(aob, wob, out, S_LEN, HIDDEN, NH * DH);
}

// Round 2
// 708.326 us; speedup vs baseline: 3.0871x; 3.0871x over previous
//
#include <hip/hip_runtime.h>
#include <hip/hip_bf16.h>

typedef __attribute__((ext_vector_type(8))) short bf16x8;
typedef __attribute__((ext_vector_type(4))) float f32x4;
typedef __hip_bfloat16 bf16;

#define S_LEN 2048
#define HIDDEN 4096
#define NH 32
#define NKV 8
#define DH 128
#define ROTD 64
#define QKVW 6144              // fused QKV row width (32*128 + 8*128 + 8*128)
#define KOFF 4096              // K column offset in fused buffer
#define VOFF 5120              // V column offset
#define ATT_SCALE 0.08838834764831845f
#define RMS_EPS 1e-6f

static __device__ __forceinline__ unsigned short f2bu(float f) {
    bf16 h = __float2bfloat16(f);
    return __builtin_bit_cast(unsigned short, h);
}

static __device__ __forceinline__ void load_lds_16(const bf16* g, bf16* l) {
    __builtin_amdgcn_global_load_lds((const __attribute__((address_space(1))) void*)g,
                                     (__attribute__((address_space(3))) void*)l, 16, 0, 0);
}

// ---------------- fp32 -> bf16 cast (vectorized float4) ----------------
__global__ __launch_bounds__(256) void cast_f32_bf16(const float* __restrict__ src,
                                                     unsigned short* __restrict__ dst, int n4) {
    int i = blockIdx.x * 256 + threadIdx.x;
    if (i >= n4) return;
    float4 v = reinterpret_cast<const float4*>(src)[i];
    ushort4 o;
    o.x = f2bu(v.x); o.y = f2bu(v.y); o.z = f2bu(v.z); o.w = f2bu(v.w);
    reinterpret_cast<ushort4*>(dst)[i] = o;
}

// ---------------- C[M,N] = A[M,K] @ B[N,K]^T, m97-style LDS-staged ----------------
// 128x128 block tile, BK=32, 256 threads. Wave w computes 64x64 (4x4 of 16x16 MFMA).
// global_load_lds width 16: LDS dest = wave-uniform base + lane*16, layout row-major [128][32].
template <typename OutT>
__global__ __launch_bounds__(256) void gemm_lds(const bf16* __restrict__ A,
                                                const bf16* __restrict__ B,
                                                OutT* __restrict__ C,
                                                int M, int N, int K) {
    __shared__ bf16 As[128 * 32];
    __shared__ bf16 Bs[128 * 32];
    const int tid  = threadIdx.x;
    const int lane = tid & 63;
    const int wave = tid >> 6;
    const int lq   = lane & 15;
    const int quad = lane >> 4;
    const int m0 = blockIdx.y * 128;
    const int n0 = blockIdx.x * 128;
    const int wm = (wave & 1) * 64;
    const int wn = (wave >> 1) * 64;

    f32x4 acc[4][4] = {};

    // staging chunks: chunk c (0..511) -> row c>>2, 8-elem col group c&3, lds elem off c*8
    const int ar = tid >> 2;            // rows 0..63 (chunk 0), +64 (chunk 1)
    const int ac = (tid & 3) * 8;
    const bf16* Ag0 = A + (size_t)(m0 + ar) * K + ac;
    const bf16* Ag1 = Ag0 + (size_t)64 * K;
    const bf16* Bg0 = B + (size_t)(n0 + ar) * K + ac;
    const bf16* Bg1 = Bg0 + (size_t)64 * K;
    bf16* Asl0 = As + wave * 512;        // (wave*64 + 0)*8
    bf16* Asl1 = As + wave * 512 + 2048; // (wave*64 + 256)*8
    bf16* Bsl0 = Bs + wave * 512;
    bf16* Bsl1 = Bs + wave * 512 + 2048;

    for (int k0 = 0; k0 < K; k0 += 32) {
        load_lds_16(Ag0 + k0, Asl0);
        load_lds_16(Ag1 + k0, Asl1);
        load_lds_16(Bg0 + k0, Bsl0);
        load_lds_16(Bg1 + k0, Bsl1);
        __syncthreads();
        bf16x8 av[4], bv[4];
#pragma unroll
        for (int i = 0; i < 4; ++i)
            av[i] = *reinterpret_cast<const bf16x8*>(As + (wm + i * 16 + lq) * 32 + quad * 8);
#pragma unroll
        for (int i = 0; i < 4; ++i)
            bv[i] = *reinterpret_cast<const bf16x8*>(Bs + (wn + i * 16 + lq) * 32 + quad * 8);
#pragma unroll
        for (int mt = 0; mt < 4; ++mt)
#pragma unroll
            for (int nt = 0; nt < 4; ++nt)
                acc[mt][nt] = __builtin_amdgcn_mfma_f32_16x16x32_bf16(av[mt], bv[nt], acc[mt][nt], 0, 0, 0);
        __syncthreads();
    }

#pragma unroll
    for (int mt = 0; mt < 4; ++mt)
#pragma unroll
        for (int nt = 0; nt < 4; ++nt)
#pragma unroll
            for (int r = 0; r < 4; ++r) {
                float v = acc[mt][nt][r];
                size_t idx = (size_t)(m0 + wm + mt * 16 + quad * 4 + r) * N + n0 + wn + nt * 16 + lq;
                if constexpr (sizeof(OutT) == 2) C[idx] = __float2bfloat16(v);
                else                             C[idx] = v;
            }
}

// ---------------- fused RMSNorm + partial RoPE (in place, strided) ----------------
// one wave per (s, head) row of 128; lane holds d=lane and d=lane+64.
__global__ __launch_bounds__(256) void norm_rope(bf16* __restrict__ buf,
                                                 const float* __restrict__ w,
                                                 const float* __restrict__ cosp,
                                                 const float* __restrict__ sinp,
                                                 int log2nh, int stride, int coloff) {
    const int lane = threadIdx.x & 63;
    const int wave = threadIdx.x >> 6;
    const int row  = blockIdx.x * 4 + wave;
    const int s    = row >> log2nh;
    const int hh   = row & ((1 << log2nh) - 1);
    bf16* p = buf + (size_t)s * stride + coloff + hh * DH;

    float x1 = __bfloat162float(p[lane]);
    float x2 = __bfloat162float(p[64 + lane]);

    float ss = x1 * x1 + x2 * x2;
#pragma unroll
    for (int off = 1; off < 64; off <<= 1) ss += __shfl_xor(ss, off);
    float rs = rsqrtf(ss * (1.0f / 128.0f) + RMS_EPS);

    float y1 = x1 * rs * w[lane];
    float y2 = x2 * rs * w[64 + lane];

    float partner = __shfl_xor(y1, 32);
    float c  = cosp[(size_t)s * ROTD + lane];
    float sn = sinp[(size_t)s * ROTD + lane];
    float rot = (lane < 32) ? (y1 * c - partner * sn) : (y1 * c + partner * sn);

    p[lane]      = __float2bfloat16(rot);
    p[64 + lane] = __float2bfloat16(y2);
}

// ---------------- V transpose: qkv V cols -> vt(NKV*DH, S) ----------------
__global__ __launch_bounds__(256) void transpose_v(const bf16* __restrict__ v,
                                                   bf16* __restrict__ vt,
                                                   int stride, int colofs) {
    __shared__ bf16 t[32][65];
    const int c0 = blockIdx.x * 32;
    const int s0 = blockIdx.y * 64;
    {
        const int j  = threadIdx.x & 31;
        const int i0 = threadIdx.x >> 5;
#pragma unroll
        for (int p = 0; p < 8; ++p) {
            int si = p * 8 + i0;
            t[j][si] = v[(size_t)(s0 + si) * stride + colofs + c0 + j];
        }
    }
    __syncthreads();
    {
        const int ii = threadIdx.x & 63;
        const int j0 = threadIdx.x >> 6;
#pragma unroll
        for (int p = 0; p < 8; ++p) {
            int c = p * 4 + j0;
            vt[(size_t)(c0 + c) * S_LEN + s0 + ii] = t[c][ii];
        }
    }
}

// ---------------- MFMA flash attention (causal, GQA) ----------------
// One q-tile (16 rows) per call; 64-key k-iterations; per-wave LDS for P C->A transpose.
static __device__ __forceinline__ void attn_one(int q0, int h, const bf16* __restrict__ QKV,
                                                const bf16* __restrict__ VT,
                                                bf16* __restrict__ O, bf16* pb,
                                                int lq, int quad) {
    const int kvh = h >> 2;   // GQA rep=4

    bf16x8 qf[4];
    const bf16* qrow = QKV + (size_t)(q0 + lq) * QKVW + h * DH + quad * 8;
#pragma unroll
    for (int i = 0; i < 4; ++i) qf[i] = *reinterpret_cast<const bf16x8*>(qrow + 32 * i);

    f32x4 o[8];
#pragma unroll
    for (int t2 = 0; t2 < 8; ++t2) o[t2] = (f32x4){0.f, 0.f, 0.f, 0.f};
    float m_i[4], l_i[4];
#pragma unroll
    for (int r = 0; r < 4; ++r) { m_i[r] = -1e30f; l_i[r] = 0.f; }

    const int limit = q0 + 16;
    for (int k0 = 0; k0 < limit; k0 += 64) {
        int nt = (limit - k0) >> 4; if (nt > 4) nt = 4;
        float p[4][4];
#pragma unroll
        for (int t = 0; t < 4; ++t) {
            if (t < nt) {
                f32x4 sacc = (f32x4){0.f, 0.f, 0.f, 0.f};
                const int kc = k0 + 16 * t;
                const bf16* kp = QKV + (size_t)(kc + lq) * QKVW + KOFF + kvh * DH + quad * 8;
#pragma unroll
                for (int i = 0; i < 4; ++i) {
                    bf16x8 kf = *reinterpret_cast<const bf16x8*>(kp + 32 * i);
                    sacc = __builtin_amdgcn_mfma_f32_16x16x32_bf16(qf[i], kf, sacc, 0, 0, 0);
                }
#pragma unroll
                for (int r = 0; r < 4; ++r) {
                    int qi = q0 + quad * 4 + r;
                    int ki = kc + lq;
                    p[t][r] = (ki > qi) ? -1e30f : sacc[r] * ATT_SCALE;
                }
            } else {
#pragma unroll
                for (int r = 0; r < 4; ++r) p[t][r] = -1e30f;
            }
        }
        float rowmax[4];
#pragma unroll
        for (int r = 0; r < 4; ++r)
            rowmax[r] = fmaxf(fmaxf(p[0][r], p[1][r]), fmaxf(p[2][r], p[3][r]));
#pragma unroll
        for (int off = 1; off < 16; off <<= 1)
#pragma unroll
            for (int r = 0; r < 4; ++r) rowmax[r] = fmaxf(rowmax[r], __shfl_xor(rowmax[r], off));

        float alpha[4];
#pragma unroll
        for (int r = 0; r < 4; ++r) {
            float mn = fmaxf(m_i[r], rowmax[r]);
            alpha[r] = __expf(m_i[r] - mn);
            m_i[r] = mn;
        }
#pragma unroll
        for (int t = 0; t < 4; ++t)
#pragma unroll
            for (int r = 0; r < 4; ++r) p[t][r] = __expf(p[t][r] - m_i[r]);

        float rsum[4];
#pragma unroll
        for (int r = 0; r < 4; ++r) rsum[r] = (p[0][r] + p[1][r]) + (p[2][r] + p[3][r]);
#pragma unroll
        for (int off = 1; off < 16; off <<= 1)
#pragma unroll
            for (int r = 0; r < 4; ++r) rsum[r] += __shfl_xor(rsum[r], off);
#pragma unroll
        for (int r = 0; r < 4; ++r) l_i[r] = l_i[r] * alpha[r] + rsum[r];

        // P (C-layout) -> LDS row-major 16x64 -> A-layout fragments
#pragma unroll
        for (int t = 0; t < 4; ++t)
#pragma unroll
            for (int r = 0; r < 4; ++r)
                pb[(quad * 4 + r) * 64 + t * 16 + lq] = __float2bfloat16(p[t][r]);
        __threadfence_block();

        // rescale O once per k-iter
#pragma unroll
        for (int t2 = 0; t2 < 8; ++t2)
#pragma unroll
            for (int r = 0; r < 4; ++r) o[t2][r] *= alpha[r];

        const int nh2 = (nt + 1) >> 1;   // 32-key halves to run
        for (int hh = 0; hh < nh2; ++hh) {
            bf16x8 pa = *reinterpret_cast<const bf16x8*>(pb + lq * 64 + hh * 32 + quad * 8);
            const bf16* vp = VT + (size_t)(kvh * DH + lq) * S_LEN + k0 + hh * 32 + quad * 8;
#pragma unroll
            for (int t2 = 0; t2 < 8; ++t2) {
                bf16x8 vf = *reinterpret_cast<const bf16x8*>(vp + (size_t)t2 * 16 * S_LEN);
                o[t2] = __builtin_amdgcn_mfma_f32_16x16x32_bf16(pa, vf, o[t2], 0, 0, 0);
            }
        }
        __threadfence_block();
    }

#pragma unroll
    for (int r = 0; r < 4; ++r) l_i[r] = 1.0f / l_i[r];
#pragma unroll
    for (int t2 = 0; t2 < 8; ++t2)
#pragma unroll
        for (int r = 0; r < 4; ++r)
            O[(size_t)(q0 + quad * 4 + r) * (NH * DH) + h * DH + t2 * 16 + lq] =
                __float2bfloat16(o[t2][r] * l_i[r]);
}

// Wave handles complementary q-tiles idx and 127-idx -> uniform 129 key-tiles per wave.
__global__ __launch_bounds__(256) void flash_attn(const bf16* __restrict__ QKV,
                                                  const bf16* __restrict__ VT,
                                                  bf16* __restrict__ O) {
    __shared__ bf16 pbuf[4][16 * 64];
    const int lane = threadIdx.x & 63;
    const int wave = threadIdx.x >> 6;
    const int lq   = lane & 15;
    const int quad = lane >> 4;
    const int w    = blockIdx.x * 4 + wave;   // 0..2047
    const int h    = w >> 6;                  // 0..31
    const int idx  = w & 63;                  // 0..63
    bf16* pb = pbuf[wave];
    attn_one(idx * 16,         h, QKV, VT, O, pb, lq, quad);
    attn_one((127 - idx) * 16, h, QKV, VT, O, pb, lq, quad);
}

extern "C" void kernel_launch(void* const* d_in, const int* in_sizes, int n_in,
                              void* d_out, int out_size, void* d_ws, size_t ws_size,
                              hipStream_t stream) {
    const float* hs   = (const float*)d_in[0];
    const float* cosp = (const float*)d_in[1];
    const float* sinp = (const float*)d_in[2];
    const float* Wq   = (const float*)d_in[3];
    const float* Wk   = (const float*)d_in[4];
    const float* Wv   = (const float*)d_in[5];
    const float* Wo   = (const float*)d_in[6];
    const float* qw   = (const float*)d_in[7];
    const float* kw   = (const float*)d_in[8];
    float* out = (float*)d_out;

    char* ws = (char*)d_ws;
    size_t off = 0;
    auto carve = [&](size_t bytes) { char* p = ws + off; off += (bytes + 255) & ~(size_t)255; return p; };

    bf16* hsb  = (bf16*)carve((size_t)S_LEN * HIDDEN * 2);          // hidden bf16; reused as AO
    bf16* wqkv = (bf16*)carve((size_t)QKVW * HIDDEN * 2);           // fused [6144, 4096]
    bf16* wob  = (bf16*)carve((size_t)HIDDEN * NH * DH * 2);
    bf16* qkv  = (bf16*)carve((size_t)S_LEN * QKVW * 2);            // [S, 6144]
    bf16* vtb  = (bf16*)carve((size_t)NKV * DH * S_LEN * 2);

    // 1. casts (Wq/Wk/Wv concatenated row-wise into wqkv)
    cast_f32_bf16<<<(S_LEN * HIDDEN / 4 + 255) / 256, 256, 0, stream>>>(hs, (unsigned short*)hsb, S_LEN * HIDDEN / 4);
    cast_f32_bf16<<<(NH * DH * HIDDEN / 4 + 255) / 256, 256, 0, stream>>>(Wq, (unsigned short*)wqkv, NH * DH * HIDDEN / 4);
    cast_f32_bf16<<<(NKV * DH * HIDDEN / 4 + 255) / 256, 256, 0, stream>>>(Wk, (unsigned short*)(wqkv + (size_t)KOFF * HIDDEN), NKV * DH * HIDDEN / 4);
    cast_f32_bf16<<<(NKV * DH * HIDDEN / 4 + 255) / 256, 256, 0, stream>>>(Wv, (unsigned short*)(wqkv + (size_t)VOFF * HIDDEN), NKV * DH * HIDDEN / 4);
    cast_f32_bf16<<<(HIDDEN * NH * DH / 4 + 255) / 256, 256, 0, stream>>>(Wo, (unsigned short*)wob, HIDDEN * NH * DH / 4);

    // 2. fused QKV projection: [2048, 4096] @ [6144, 4096]^T -> [2048, 6144] bf16
    gemm_lds<bf16><<<dim3(QKVW / 128, S_LEN / 128), 256, 0, stream>>>(hsb, wqkv, qkv, S_LEN, QKVW, HIDDEN);

    // 3. rmsnorm + rope in place on Q and K slices
    norm_rope<<<S_LEN * NH / 4, 256, 0, stream>>>(qkv, qw, cosp, sinp, 5, QKVW, 0);
    norm_rope<<<S_LEN * NKV / 4, 256, 0, stream>>>(qkv, kw, cosp, sinp, 3, QKVW, KOFF);

    // 4. V transpose from qkv cols [5120,6144) -> vt[1024, 2048]
    transpose_v<<<dim3(NKV * DH / 32, S_LEN / 64), 256, 0, stream>>>(qkv, vtb, QKVW, VOFF);

    // 5. flash attention -> AO (reuse hsb)
    bf16* aob = hsb;
    flash_attn<<<NH * 64 / 4, 256, 0, stream>>>(qkv, vtb, aob);

    // 6. output projection (fp32 out)
    gemm_lds<float><<<dim3(HIDDEN / 128, S_LEN / 128), 256, 0, stream>>>(aob, wob, out, S_LEN, HIDDEN, NH * DH);
}